// Round 15
// baseline (172.497 us; speedup 1.0000x reference)
//
#include <hip/hip_runtime.h>
#include <hip/hip_bf16.h>
#include <stdint.h>

#define B_ 16
#define N_ 2500

typedef unsigned short u16;
typedef __attribute__((ext_vector_type(8))) short bf16x8;
typedef __attribute__((ext_vector_type(4))) float f32x4;

// cold-path manual RNE (k_pack only)
__device__ __forceinline__ u16 f2bf_sw(float f) {
  unsigned u = __float_as_uint(f);
  return (u16)((u + 0x7fffu + ((u >> 16) & 1u)) >> 16);
}
// hot-path HW convert
__device__ __forceinline__ u16 f2bf(float f) {
  __hip_bfloat16 h = __float2bfloat16(f);
  return __builtin_bit_cast(u16, h);
}
__device__ __forceinline__ unsigned f2bf2(float lo, float hi) {
  return (unsigned)f2bf(lo) | ((unsigned)f2bf(hi) << 16);
}
__device__ __forceinline__ float sigm(float x) {
  return __builtin_amdgcn_rcpf(1.f + __expf(-x));
}

// Blob layout (u32 units): th 0..6144, eW 6144..7680, gW 7680..8704,
// w1 8704..9216, w2 9216..9728, nW2 frags 9728..11776, params(f32) 11776..12448.
#define BLOB_U32 12448

// ---------- kernel P: pack all weights into fragment blob ----------
__global__ __launch_bounds__(256) void k_pack(
    const float* __restrict__ theta, const float* __restrict__ edgeW,
    const float* __restrict__ gateW, const float* __restrict__ wW1,
    const float* __restrict__ wW2, const float* __restrict__ nW2,
    const float* __restrict__ theta_b, const float* __restrict__ gate_b,
    const float* __restrict__ edge_b,
    const float* __restrict__ ws1, const float* __restrict__ wb1, const float* __restrict__ wsh1,
    const float* __restrict__ ns2, const float* __restrict__ nb2, const float* __restrict__ nsh2,
    const float* __restrict__ ws2, const float* __restrict__ wb2, const float* __restrict__ wsh2,
    unsigned* __restrict__ blob) {
  const int tid = threadIdx.x;
  for (int q = tid; q < 6144; q += 256) {  // theta frags: f = t*8 + mt*2 + h
    int f = q >> 8, lane = (q >> 2) & 63, jp = q & 3;
    int t = f >> 3, mt = (f >> 1) & 3, h = f & 1;
    int el = lane & 15, kg = lane >> 4;
    const float* s = theta + ((size_t)t * 64 + mt * 16 + el) * 64 + h * 32 + kg * 8 + jp * 2;
    blob[q] = (unsigned)f2bf_sw(s[0]) | ((unsigned)f2bf_sw(s[1]) << 16);
  }
  for (int q = tid; q < 1536; q += 256) {  // edgeW frags: f = mt*3 + s
    int f = q >> 8, lane = (q >> 2) & 63, jp = q & 3;
    int mt = f / 3, ss = f - mt * 3;
    int el = lane & 15, kg = lane >> 4;
    const float* s = edgeW + ((size_t)mt * 16 + el) * 96 + ss * 32 + kg * 8 + jp * 2;
    blob[6144 + q] = (unsigned)f2bf_sw(s[0]) | ((unsigned)f2bf_sw(s[1]) << 16);
  }
  for (int q = tid; q < 1024; q += 256) {  // gateW frags: f = mt
    int f = q >> 8, lane = (q >> 2) & 63, jp = q & 3;
    int el = lane & 15, kg = lane >> 4;
    const float* s = gateW + ((size_t)f * 16 + el) * 32 + kg * 8 + jp * 2;
    blob[7680 + q] = (unsigned)f2bf_sw(s[0]) | ((unsigned)f2bf_sw(s[1]) << 16);
  }
  for (int q = tid; q < 512; q += 256) {  // wW1/wW2 frags: f = mt
    int f = q >> 8, lane = (q >> 2) & 63, jp = q & 3;
    int el = lane & 15, kg = lane >> 4;
    const float* s1 = wW1 + (size_t)(f * 16 + el) * 32 + kg * 8 + jp * 2;
    const float* s2 = wW2 + (size_t)(f * 16 + el) * 32 + kg * 8 + jp * 2;
    blob[8704 + q] = (unsigned)f2bf_sw(s1[0]) | ((unsigned)f2bf_sw(s1[1]) << 16);
    blob[9216 + q] = (unsigned)f2bf_sw(s2[0]) | ((unsigned)f2bf_sw(s2[1]) << 16);
  }
  for (int q = tid; q < 2048; q += 256) {  // nW2 frags: f = mt*2 + h
    int f = q >> 8, lane = (q >> 2) & 63, jp = q & 3;
    int mt = f >> 1, h = f & 1;
    int el = lane & 15, kg = lane >> 4;
    const float* s = nW2 + (size_t)(mt * 16 + el) * 64 + h * 32 + kg * 8 + jp * 2;
    blob[9728 + q] = (unsigned)f2bf_sw(s[0]) | ((unsigned)f2bf_sw(s[1]) << 16);
  }
  float* bf = (float*)blob;
  for (int i = tid; i < 672; i += 256) {
    float v;
    if (i < 192)      v = theta_b[i];
    else if (i < 256) v = gate_b[i - 192];
    else if (i < 320) v = ns2[i - 256];
    else if (i < 384) v = nb2[i - 320];
    else if (i < 448) v = nsh2[i - 384];
    else if (i < 480) v = edge_b[i - 448];
    else if (i < 512) v = ws1[i - 480];
    else if (i < 544) v = wb1[i - 512];
    else if (i < 576) v = wsh1[i - 544];
    else if (i < 608) v = ws2[i - 576];
    else if (i < 640) v = wb2[i - 608];
    else              v = wsh2[i - 640];
    bf[11776 + i] = v;
  }
}

// ---------- kernel A: nf1 = relu(bn(nW1 @ node)) -> bf16 [b*N+n][64], MFMA ----------
__global__ __launch_bounds__(256) void k_nf1(
    const float* __restrict__ node, const float* __restrict__ W,
    const float* __restrict__ bia, const float* __restrict__ sc,
    const float* __restrict__ sh, u16* __restrict__ nf1b) {
  __shared__ __align__(16) u16 W_p[8 * 64 * 8];
  __shared__ float bia_s[64], sc_s[64], sh_s[64];
  const int tid = threadIdx.x;
  for (int q = tid; q < 2048; q += 256) {
    int f = q >> 8, lane = (q >> 2) & 63, jp = q & 3;
    int mt = f >> 1, h = f & 1;
    int fel = lane & 15, fkg = lane >> 4;
    const float* src = W + (size_t)(mt * 16 + fel) * 64 + h * 32 + fkg * 8 + jp * 2;
    ((unsigned*)W_p)[q] = f2bf2(src[0], src[1]);
  }
  if (tid < 64) { bia_s[tid] = bia[tid]; sc_s[tid] = sc[tid]; sh_s[tid] = sh[tid]; }
  __syncthreads();

  const int l = tid & 63, wv = tid >> 6;
  const int el = l & 15, kg = l >> 4;
  const int bn = blockIdx.x * 64 + wv * 16 + el;
  const int b = bn / N_;
  const int n = bn - b * N_;

  union UF { bf16x8 v; uint4 q; } xb0, xb1;
  const float* xp0 = node + (size_t)(b * 64 + kg * 8) * N_ + n;
  const float* xp1 = node + (size_t)(b * 64 + 32 + kg * 8) * N_ + n;
  {
    float a0[8], a1[8];
#pragma unroll
    for (int j = 0; j < 8; ++j) { a0[j] = xp0[(size_t)j * N_]; a1[j] = xp1[(size_t)j * N_]; }
    xb0.q.x = f2bf2(a0[0], a0[1]); xb0.q.y = f2bf2(a0[2], a0[3]);
    xb0.q.z = f2bf2(a0[4], a0[5]); xb0.q.w = f2bf2(a0[6], a0[7]);
    xb1.q.x = f2bf2(a1[0], a1[1]); xb1.q.y = f2bf2(a1[2], a1[3]);
    xb1.q.z = f2bf2(a1[4], a1[5]); xb1.q.w = f2bf2(a1[6], a1[7]);
  }
  const f32x4 z4 = {0.f, 0.f, 0.f, 0.f};
#pragma unroll
  for (int mt = 0; mt < 4; ++mt) {
    bf16x8 a0 = *(const bf16x8*)&W_p[((mt * 2 + 0) * 64 + l) * 8];
    bf16x8 a1 = *(const bf16x8*)&W_p[((mt * 2 + 1) * 64 + l) * 8];
    f32x4 acc = __builtin_amdgcn_mfma_f32_16x16x32_bf16(a0, xb0.v, z4, 0, 0, 0);
    acc = __builtin_amdgcn_mfma_f32_16x16x32_bf16(a1, xb1.v, acc, 0, 0, 0);
    int ob = mt * 16 + kg * 4;
    float4 s4 = *(const float4*)&sc_s[ob];
    float4 b4 = *(const float4*)&bia_s[ob];
    float4 h4 = *(const float4*)&sh_s[ob];
    uint2 d;
    d.x = f2bf2(fmaxf(fmaf(s4.x, acc[0] + b4.x, h4.x), 0.f),
                fmaxf(fmaf(s4.y, acc[1] + b4.y, h4.y), 0.f));
    d.y = f2bf2(fmaxf(fmaf(s4.z, acc[2] + b4.z, h4.z), 0.f),
                fmaxf(fmaf(s4.w, acc[3] + b4.w, h4.w), 0.f));
    *(uint2*)&nf1b[(size_t)bn * 64 + ob] = d;
  }
}

// ---------- kernel B: fused MFMA message passing, register-slim + prefetch ----------
// R14 base (slim body, setprio) + full 1-deep prefetch of idx/et/nb/x.
// Slim body (~124 regs total) + ~16 prefetch regs fits the (256,3) 170 cap.
__global__ __launch_bounds__(256, 3) void k_fused(
    const float* __restrict__ node, const float* __restrict__ wfeat,
    const int* __restrict__ etype, const int* __restrict__ nn_idx,
    const u16* __restrict__ nf1b, const unsigned* __restrict__ blob,
    float* __restrict__ out_nf, float* __restrict__ out_wf) {

  __shared__ __align__(16) unsigned char sm[41600];  // 38912 frags + 2688 params
  __shared__ __align__(16) u16 nout_bf[16 * 64];     // 2048 B, swizzled
  __shared__ __align__(16) u16 Rx[4][512];           // 4096 B

  const int tid = threadIdx.x;
  for (int i = tid; i < 2432; i += 256)              // frag part: 9728 u32
    ((uint4*)sm)[i] = ((const uint4*)blob)[i];
  for (int i = tid; i < 168; i += 256)               // params: 672 u32
    ((uint4*)(sm + 38912))[i] = ((const uint4*)(blob + 11776))[i];

  const u16* th_p = (const u16*)sm;
  const u16* eW_p = (const u16*)(sm + 24576);
  const u16* gW_p = (const u16*)(sm + 30720);
  const u16* w1_p = (const u16*)(sm + 34816);
  const u16* w2_p = (const u16*)(sm + 36864);
  const float* par = (const float*)(sm + 38912);
  const float* tb_s  = par;
  const float* gb_s  = par + 192;
  const float* ns2_s = par + 256;
  const float* nb2_s = par + 320;
  const float* nsh2_s= par + 384;
  const float* eb_s  = par + 448;
  const float* ws1_s = par + 480;
  const float* wb1_s = par + 512;
  const float* wsh1_s= par + 544;
  const float* ws2_s = par + 576;
  const float* wb2_s = par + 608;
  const float* wsh2_s= par + 640;

  // bijective XCD chunking: nwg=2500, q=312, r=4
  const int pb = blockIdx.x;
  const int xcd = pb & 7, sub = pb >> 3;
  const int lb = (xcd < 4) ? (xcd * 313 + sub) : (1252 + (xcd - 4) * 312 + sub);
  const int nbase = lb * 16;

  const int l = tid & 63, wv = tid >> 6;  // wv 0..3
  const int el = l & 15, kg = l >> 4;
  u16* const Rn = &Rx[wv][0];
  const int eoff = nbase * 16 + wv * 16 + el;  // edge-array base for this lane

  __syncthreads();

  const f32x4 z4 = {0.f, 0.f, 0.f, 0.f};
  union UF { bf16x8 v; uint4 q; };

  // ---- 1-deep full prefetch state: idx/et + nb frags + x frag ----
  int et_c;
  bf16x8 nb0_c, nb1_c;
  UF x_c;
  {
    const int nid = nbase + wv;
    const int b = nid / N_, n = nid - b * N_;
    const int idx0 = nn_idx[eoff];
    et_c = etype[eoff];
    const u16* nbp = nf1b + ((size_t)b * N_ + idx0) * 64 + kg * 8;
    nb0_c = *(const bf16x8*)nbp;
    nb1_c = *(const bf16x8*)(nbp + 32);
    const float* xp = wfeat + ((size_t)(b * 32 + kg * 8) * N_ + n) * 16 + el;
    float a[8];
#pragma unroll
    for (int j = 0; j < 8; ++j) a[j] = xp[(size_t)j * N_ * 16];
    x_c.q.x = f2bf2(a[0], a[1]); x_c.q.y = f2bf2(a[2], a[3]);
    x_c.q.z = f2bf2(a[4], a[5]); x_c.q.w = f2bf2(a[6], a[7]);
  }

#pragma unroll 1
  for (int it = 0; it < 4; ++it) {
    const int nid = nbase + it * 4 + wv;
    const int b = nid / N_;
    const int n = nid - b * N_;
    const int nl = it * 4 + wv;  // 0..15

    const int et = et_c;
    const bf16x8 nbf0 = nb0_c, nbf1 = nb1_c;
    const UF xf = x_c;

    // ---- issue next node's loads early (consumed next iteration) ----
    if (it < 3) {
      const int nid2 = nbase + (it + 1) * 4 + wv;
      const int b2 = nid2 / N_, n2 = nid2 - b2 * N_;
      const int idxn = nn_idx[eoff + (it + 1) * 64];
      et_c = etype[eoff + (it + 1) * 64];
      const u16* nbp = nf1b + ((size_t)b2 * N_ + idxn) * 64 + kg * 8;
      nb0_c = *(const bf16x8*)nbp;
      nb1_c = *(const bf16x8*)(nbp + 32);
      const float* xp = wfeat + ((size_t)(b2 * 32 + kg * 8) * N_ + n2) * 16 + el;
      float a[8];
#pragma unroll
      for (int j = 0; j < 8; ++j) a[j] = xp[(size_t)j * N_ * 16];
      x_c.q.x = f2bf2(a[0], a[1]); x_c.q.y = f2bf2(a[2], a[3]);
      x_c.q.z = f2bf2(a[4], a[5]); x_c.q.w = f2bf2(a[6], a[7]);
    }

    // ---- wf1 = relu(bn(wW1 @ x)) -> R ----
#pragma unroll
    for (int mt = 0; mt < 2; ++mt) {
      bf16x8 a = *(const bf16x8*)&w1_p[(mt * 64 + l) * 8];
      f32x4 wc = __builtin_amdgcn_mfma_f32_16x16x32_bf16(a, xf.v, z4, 0, 0, 0);
      int ob = mt * 16 + kg * 4;
      float4 s4 = *(const float4*)&ws1_s[ob];
      float4 b4 = *(const float4*)&wb1_s[ob];
      float4 h4 = *(const float4*)&wsh1_s[ob];
      uint2 d;
      d.x = f2bf2(fmaxf(fmaf(s4.x, wc[0] + b4.x, h4.x), 0.f),
                  fmaxf(fmaf(s4.y, wc[1] + b4.y, h4.y), 0.f));
      d.y = f2bf2(fmaxf(fmaf(s4.z, wc[2] + b4.z, h4.z), 0.f),
                  fmaxf(fmaf(s4.w, wc[3] + b4.w, h4.w), 0.f));
      *(uint2*)&Rn[((mt * 2 + (kg >> 1)) * 16 + el) * 8 + (kg & 1) * 4] = d;
    }
    const bf16x8 wff = *(const bf16x8*)&Rn[l * 8];

    // ---- fused gate + msg + reduce, per M-tile; only w4r[4] persists ----
    const unsigned mk0 = (et == 0) ? 0xffffffffu : 0u;
    const unsigned mk1 = (et == 1) ? 0xffffffffu : 0u;
    const unsigned mk2 = (et == 2) ? 0xffffffffu : 0u;
    const int b0s = el & 1, b1s = (el >> 1) & 1;
    float w4r[4];
#pragma unroll 2
    for (int mt = 0; mt < 4; ++mt) {
      // gate tile (K=32 over wf1)
      bf16x8 ga = *(const bf16x8*)&gW_p[(mt * 64 + l) * 8];
      __builtin_amdgcn_s_setprio(1);
      f32x4 gacc = __builtin_amdgcn_mfma_f32_16x16x32_bf16(ga, wff, z4, 0, 0, 0);
      // msg tile: 3 etypes x 2 K-steps into one f32x4
      f32x4 m4 = z4;
#pragma unroll
      for (int t = 0; t < 3; ++t) {
        unsigned msk = (t == 0) ? mk0 : ((t == 1) ? mk1 : mk2);
        UF b0u, b1u;
        b0u.v = nbf0; b1u.v = nbf1;
        b0u.q.x &= msk; b0u.q.y &= msk; b0u.q.z &= msk; b0u.q.w &= msk;
        b1u.q.x &= msk; b1u.q.y &= msk; b1u.q.z &= msk; b1u.q.w &= msk;
        bf16x8 a0 = *(const bf16x8*)&th_p[((t * 8 + mt * 2 + 0) * 64 + l) * 8];
        bf16x8 a1 = *(const bf16x8*)&th_p[((t * 8 + mt * 2 + 1) * 64 + l) * 8];
        m4 = __builtin_amdgcn_mfma_f32_16x16x32_bf16(a0, b0u.v, m4, 0, 0, 0);
        m4 = __builtin_amdgcn_mfma_f32_16x16x32_bf16(a1, b1u.v, m4, 0, 0, 0);
      }
      __builtin_amdgcn_s_setprio(0);
      // combine + sigmoid
      int ob = mt * 16 + kg * 4;
      float4 tb = *(const float4*)&tb_s[et * 64 + ob];
      float4 gb = *(const float4*)&gb_s[ob];
      float p0 = (m4[0] + tb.x) * sigm(gacc[0] + gb.x);
      float p1 = (m4[1] + tb.y) * sigm(gacc[1] + gb.y);
      float p2 = (m4[2] + tb.z) * sigm(gacc[2] + gb.z);
      float p3 = (m4[3] + tb.w) * sigm(gacc[3] + gb.w);
      // reduce stage 1 (xor 1) -> two survivors, stage 2 (xor 2) -> one
      float s, k0;
      s = b0s ? p0 : p1; k0 = b0s ? p1 : p0;
      float w8a = k0 + __shfl_xor(s, 1);
      s = b0s ? p2 : p3; k0 = b0s ? p3 : p2;
      float w8b = k0 + __shfl_xor(s, 1);
      s = b1s ? w8a : w8b; k0 = b1s ? w8b : w8a;
      w4r[mt] = k0 + __shfl_xor(s, 2);
    }
    // reduce stages 3-4
    {
      const int b2s = (el >> 2) & 1, b3s = (el >> 3) & 1;
      float s, k0;
      s = b2s ? w4r[0] : w4r[1]; k0 = b2s ? w4r[1] : w4r[0];
      float w2a = k0 + __shfl_xor(s, 4);
      s = b2s ? w4r[2] : w4r[3]; k0 = b2s ? w4r[3] : w4r[2];
      float w2b = k0 + __shfl_xor(s, 4);
      s = b3s ? w2a : w2b; k0 = b3s ? w2b : w2a;
      float z = k0 + __shfl_xor(s, 8);
      float no = fmaxf(z * 0.0625f, 0.f);
      int ch = ((el >> 2) << 4) + (kg << 2) + (el & 3);
      int su = (ch >> 3) ^ (nl & 7);
      nout_bf[nl * 64 + su * 8 + (ch & 7)] = f2bf(no);
    }

    // ---- edge conv + w_out epilogue (eacc transient per tile) -> R ----
    __builtin_amdgcn_s_setprio(1);
#pragma unroll
    for (int mt = 0; mt < 2; ++mt) {
      bf16x8 a0 = *(const bf16x8*)&eW_p[((mt * 3 + 0) * 64 + l) * 8];
      bf16x8 a1 = *(const bf16x8*)&eW_p[((mt * 3 + 1) * 64 + l) * 8];
      bf16x8 a2 = *(const bf16x8*)&eW_p[((mt * 3 + 2) * 64 + l) * 8];
      f32x4 acc = __builtin_amdgcn_mfma_f32_16x16x32_bf16(a0, wff, z4, 0, 0, 0);
      acc = __builtin_amdgcn_mfma_f32_16x16x32_bf16(a1, nbf0, acc, 0, 0, 0);
      acc = __builtin_amdgcn_mfma_f32_16x16x32_bf16(a2, nbf1, acc, 0, 0, 0);
      int ob = mt * 16 + kg * 4;
      float4 eb4 = *(const float4*)&eb_s[ob];
      uint2 d;
      d.x = f2bf2(fmaxf(acc[0] + eb4.x, 0.f), fmaxf(acc[1] + eb4.y, 0.f));
      d.y = f2bf2(fmaxf(acc[2] + eb4.z, 0.f), fmaxf(acc[3] + eb4.w, 0.f));
      *(uint2*)&Rn[((mt * 2 + (kg >> 1)) * 16 + el) * 8 + (kg & 1) * 4] = d;
    }
    __builtin_amdgcn_s_setprio(0);
    const bf16x8 wof = *(const bf16x8*)&Rn[l * 8];

    // ---- wf2 = relu(bn(wW2 @ w_out)) + wfeat residual, direct store ----
#pragma unroll
    for (int mt = 0; mt < 2; ++mt) {
      bf16x8 a = *(const bf16x8*)&w2_p[(mt * 64 + l) * 8];
      f32x4 fc = __builtin_amdgcn_mfma_f32_16x16x32_bf16(a, wof, z4, 0, 0, 0);
      int ob = mt * 16 + kg * 4;
      float4 s4 = *(const float4*)&ws2_s[ob];
      float4 b4 = *(const float4*)&wb2_s[ob];
      float4 h4 = *(const float4*)&wsh2_s[ob];
      float sv[4] = {s4.x, s4.y, s4.z, s4.w};
      float bv[4] = {b4.x, b4.y, b4.z, b4.w};
      float hv[4] = {h4.x, h4.y, h4.z, h4.w};
#pragma unroll
      for (int r = 0; r < 4; ++r) {
        int a2 = ((b * 32 + ob + r) * N_ + n) * 16 + el;
        float y = fmaxf(fmaf(sv[r], fc[r] + bv[r], hv[r]), 0.f);
        out_wf[a2] = y + wfeat[a2];
      }
    }
  }
  __syncthreads();

  // ---- phase 2: nf2 = relu(bn(nW2 @ n_out)) + node residual, via MFMA ----
  // 4 waves: wave wv = M-tile; 16 nodes; nW2 frags direct from global blob.
  {
    const int mt = wv;
    const int node_l = el;
    const int nid2 = nbase + node_l;
    const int b2 = nid2 / N_;
    const int n2 = nid2 - b2 * N_;
    const int sw = node_l & 7;
    const u16* nW2g = (const u16*)(blob + 9728);
    bf16x8 nb0 = *(const bf16x8*)&nout_bf[node_l * 64 + ((0 + kg) ^ sw) * 8];
    bf16x8 nb1 = *(const bf16x8*)&nout_bf[node_l * 64 + ((4 + kg) ^ sw) * 8];
    bf16x8 a0 = *(const bf16x8*)&nW2g[((mt * 2 + 0) * 64 + l) * 8];
    bf16x8 a1 = *(const bf16x8*)&nW2g[((mt * 2 + 1) * 64 + l) * 8];
    f32x4 acc = __builtin_amdgcn_mfma_f32_16x16x32_bf16(a0, nb0, z4, 0, 0, 0);
    acc = __builtin_amdgcn_mfma_f32_16x16x32_bf16(a1, nb1, acc, 0, 0, 0);
#pragma unroll
    for (int i = 0; i < 4; ++i) {
      int ch = mt * 16 + kg * 4 + i;
      int off = (b2 * 64 + ch) * N_ + n2;
      float y = fmaxf(fmaf(ns2_s[ch], acc[i] + nb2_s[ch], nsh2_s[ch]), 0.f);
      out_nf[off] = y + node[off];
    }
  }
}

extern "C" void kernel_launch(void* const* d_in, const int* in_sizes, int n_in,
                              void* d_out, int out_size, void* d_ws, size_t ws_size,
                              hipStream_t stream) {
  const float* node    = (const float*)d_in[0];
  const float* wfeat   = (const float*)d_in[1];
  const int*   etype   = (const int*)d_in[2];
  const int*   nn_idx  = (const int*)d_in[3];
  const float* nW1     = (const float*)d_in[4];
  const float* nb1     = (const float*)d_in[5];
  const float* ns1     = (const float*)d_in[6];
  const float* nsh1    = (const float*)d_in[7];
  const float* wW1     = (const float*)d_in[8];
  const float* wb1     = (const float*)d_in[9];
  const float* ws1     = (const float*)d_in[10];
  const float* wsh1    = (const float*)d_in[11];
  const float* theta   = (const float*)d_in[12];
  const float* theta_b = (const float*)d_in[13];
  const float* gateW   = (const float*)d_in[14];
  const float* gate_b  = (const float*)d_in[15];
  const float* edgeW   = (const float*)d_in[16];
  const float* edge_b  = (const float*)d_in[17];
  const float* nW2     = (const float*)d_in[18];
  const float* nb2     = (const float*)d_in[19];
  const float* ns2     = (const float*)d_in[20];
  const float* nsh2    = (const float*)d_in[21];
  const float* wW2     = (const float*)d_in[22];
  const float* wb2     = (const float*)d_in[23];
  const float* ws2     = (const float*)d_in[24];
  const float* wsh2    = (const float*)d_in[25];

  u16*      nf1b = (u16*)d_ws;                                   // 5.12 MB
  unsigned* blob = (unsigned*)((char*)d_ws + 5120000);           // 49.8 KB
  float* out_nf = (float*)d_out;
  float* out_wf = (float*)d_out + (size_t)B_ * 64 * N_;

  k_pack<<<1, 256, 0, stream>>>(theta, edgeW, gateW, wW1, wW2, nW2,
                                theta_b, gate_b, edge_b,
                                ws1, wb1, wsh1, ns2, nb2, nsh2, ws2, wb2, wsh2,
                                blob);
  k_nf1<<<625, 256, 0, stream>>>(node, nW1, nb1, ns1, nsh1, nf1b);
  k_fused<<<2500, 256, 0, stream>>>(node, wfeat, etype, nn_idx, nf1b, blob,
                                    out_nf, out_wf);
}

// Round 16
// 150.036 us; speedup vs baseline: 1.1497x; 1.1497x over previous
//
#include <hip/hip_runtime.h>
#include <hip/hip_bf16.h>
#include <stdint.h>

#define B_ 16
#define N_ 2500

typedef unsigned short u16;
typedef __attribute__((ext_vector_type(8))) short bf16x8;
typedef __attribute__((ext_vector_type(4))) float f32x4;

// cold-path manual RNE (k_pack only)
__device__ __forceinline__ u16 f2bf_sw(float f) {
  unsigned u = __float_as_uint(f);
  return (u16)((u + 0x7fffu + ((u >> 16) & 1u)) >> 16);
}
// hot-path HW convert
__device__ __forceinline__ u16 f2bf(float f) {
  __hip_bfloat16 h = __float2bfloat16(f);
  return __builtin_bit_cast(u16, h);
}
__device__ __forceinline__ unsigned f2bf2(float lo, float hi) {
  return (unsigned)f2bf(lo) | ((unsigned)f2bf(hi) << 16);
}
__device__ __forceinline__ float sigm(float x) {
  return __builtin_amdgcn_rcpf(1.f + __expf(-x));
}

// Blob layout (u32 units): th 0..6144, eW 6144..7680, gW 7680..8704,
// w1 8704..9216, w2 9216..9728, nW2 frags 9728..11776, params(f32) 11776..12448.
#define BLOB_U32 12448

// ---------- kernel P: pack all weights into fragment blob ----------
__global__ __launch_bounds__(256) void k_pack(
    const float* __restrict__ theta, const float* __restrict__ edgeW,
    const float* __restrict__ gateW, const float* __restrict__ wW1,
    const float* __restrict__ wW2, const float* __restrict__ nW2,
    const float* __restrict__ theta_b, const float* __restrict__ gate_b,
    const float* __restrict__ edge_b,
    const float* __restrict__ ws1, const float* __restrict__ wb1, const float* __restrict__ wsh1,
    const float* __restrict__ ns2, const float* __restrict__ nb2, const float* __restrict__ nsh2,
    const float* __restrict__ ws2, const float* __restrict__ wb2, const float* __restrict__ wsh2,
    unsigned* __restrict__ blob) {
  const int tid = threadIdx.x;
  for (int q = tid; q < 6144; q += 256) {  // theta frags: f = t*8 + mt*2 + h
    int f = q >> 8, lane = (q >> 2) & 63, jp = q & 3;
    int t = f >> 3, mt = (f >> 1) & 3, h = f & 1;
    int el = lane & 15, kg = lane >> 4;
    const float* s = theta + ((size_t)t * 64 + mt * 16 + el) * 64 + h * 32 + kg * 8 + jp * 2;
    blob[q] = (unsigned)f2bf_sw(s[0]) | ((unsigned)f2bf_sw(s[1]) << 16);
  }
  for (int q = tid; q < 1536; q += 256) {  // edgeW frags: f = mt*3 + s
    int f = q >> 8, lane = (q >> 2) & 63, jp = q & 3;
    int mt = f / 3, ss = f - mt * 3;
    int el = lane & 15, kg = lane >> 4;
    const float* s = edgeW + ((size_t)mt * 16 + el) * 96 + ss * 32 + kg * 8 + jp * 2;
    blob[6144 + q] = (unsigned)f2bf_sw(s[0]) | ((unsigned)f2bf_sw(s[1]) << 16);
  }
  for (int q = tid; q < 1024; q += 256) {  // gateW frags: f = mt
    int f = q >> 8, lane = (q >> 2) & 63, jp = q & 3;
    int el = lane & 15, kg = lane >> 4;
    const float* s = gateW + ((size_t)f * 16 + el) * 32 + kg * 8 + jp * 2;
    blob[7680 + q] = (unsigned)f2bf_sw(s[0]) | ((unsigned)f2bf_sw(s[1]) << 16);
  }
  for (int q = tid; q < 512; q += 256) {  // wW1/wW2 frags: f = mt
    int f = q >> 8, lane = (q >> 2) & 63, jp = q & 3;
    int el = lane & 15, kg = lane >> 4;
    const float* s1 = wW1 + (size_t)(f * 16 + el) * 32 + kg * 8 + jp * 2;
    const float* s2 = wW2 + (size_t)(f * 16 + el) * 32 + kg * 8 + jp * 2;
    blob[8704 + q] = (unsigned)f2bf_sw(s1[0]) | ((unsigned)f2bf_sw(s1[1]) << 16);
    blob[9216 + q] = (unsigned)f2bf_sw(s2[0]) | ((unsigned)f2bf_sw(s2[1]) << 16);
  }
  for (int q = tid; q < 2048; q += 256) {  // nW2 frags: f = mt*2 + h
    int f = q >> 8, lane = (q >> 2) & 63, jp = q & 3;
    int mt = f >> 1, h = f & 1;
    int el = lane & 15, kg = lane >> 4;
    const float* s = nW2 + (size_t)(mt * 16 + el) * 64 + h * 32 + kg * 8 + jp * 2;
    blob[9728 + q] = (unsigned)f2bf_sw(s[0]) | ((unsigned)f2bf_sw(s[1]) << 16);
  }
  float* bf = (float*)blob;
  for (int i = tid; i < 672; i += 256) {
    float v;
    if (i < 192)      v = theta_b[i];
    else if (i < 256) v = gate_b[i - 192];
    else if (i < 320) v = ns2[i - 256];
    else if (i < 384) v = nb2[i - 320];
    else if (i < 448) v = nsh2[i - 384];
    else if (i < 480) v = edge_b[i - 448];
    else if (i < 512) v = ws1[i - 480];
    else if (i < 544) v = wb1[i - 512];
    else if (i < 576) v = wsh1[i - 544];
    else if (i < 608) v = ws2[i - 576];
    else if (i < 640) v = wb2[i - 608];
    else              v = wsh2[i - 640];
    bf[11776 + i] = v;
  }
}

// ---------- kernel A: nf1 = relu(bn(nW1 @ node)) -> bf16 [b*N+n][64], MFMA ----------
__global__ __launch_bounds__(256) void k_nf1(
    const float* __restrict__ node, const float* __restrict__ W,
    const float* __restrict__ bia, const float* __restrict__ sc,
    const float* __restrict__ sh, u16* __restrict__ nf1b) {
  __shared__ __align__(16) u16 W_p[8 * 64 * 8];
  __shared__ float bia_s[64], sc_s[64], sh_s[64];
  const int tid = threadIdx.x;
  for (int q = tid; q < 2048; q += 256) {
    int f = q >> 8, lane = (q >> 2) & 63, jp = q & 3;
    int mt = f >> 1, h = f & 1;
    int fel = lane & 15, fkg = lane >> 4;
    const float* src = W + (size_t)(mt * 16 + fel) * 64 + h * 32 + fkg * 8 + jp * 2;
    ((unsigned*)W_p)[q] = f2bf2(src[0], src[1]);
  }
  if (tid < 64) { bia_s[tid] = bia[tid]; sc_s[tid] = sc[tid]; sh_s[tid] = sh[tid]; }
  __syncthreads();

  const int l = tid & 63, wv = tid >> 6;
  const int el = l & 15, kg = l >> 4;
  const int bn = blockIdx.x * 64 + wv * 16 + el;
  const int b = bn / N_;
  const int n = bn - b * N_;

  union UF { bf16x8 v; uint4 q; } xb0, xb1;
  const float* xp0 = node + (size_t)(b * 64 + kg * 8) * N_ + n;
  const float* xp1 = node + (size_t)(b * 64 + 32 + kg * 8) * N_ + n;
  {
    float a0[8], a1[8];
#pragma unroll
    for (int j = 0; j < 8; ++j) { a0[j] = xp0[(size_t)j * N_]; a1[j] = xp1[(size_t)j * N_]; }
    xb0.q.x = f2bf2(a0[0], a0[1]); xb0.q.y = f2bf2(a0[2], a0[3]);
    xb0.q.z = f2bf2(a0[4], a0[5]); xb0.q.w = f2bf2(a0[6], a0[7]);
    xb1.q.x = f2bf2(a1[0], a1[1]); xb1.q.y = f2bf2(a1[2], a1[3]);
    xb1.q.z = f2bf2(a1[4], a1[5]); xb1.q.w = f2bf2(a1[6], a1[7]);
  }
  const f32x4 z4 = {0.f, 0.f, 0.f, 0.f};
#pragma unroll
  for (int mt = 0; mt < 4; ++mt) {
    bf16x8 a0 = *(const bf16x8*)&W_p[((mt * 2 + 0) * 64 + l) * 8];
    bf16x8 a1 = *(const bf16x8*)&W_p[((mt * 2 + 1) * 64 + l) * 8];
    f32x4 acc = __builtin_amdgcn_mfma_f32_16x16x32_bf16(a0, xb0.v, z4, 0, 0, 0);
    acc = __builtin_amdgcn_mfma_f32_16x16x32_bf16(a1, xb1.v, acc, 0, 0, 0);
    int ob = mt * 16 + kg * 4;
    float4 s4 = *(const float4*)&sc_s[ob];
    float4 b4 = *(const float4*)&bia_s[ob];
    float4 h4 = *(const float4*)&sh_s[ob];
    uint2 d;
    d.x = f2bf2(fmaxf(fmaf(s4.x, acc[0] + b4.x, h4.x), 0.f),
                fmaxf(fmaf(s4.y, acc[1] + b4.y, h4.y), 0.f));
    d.y = f2bf2(fmaxf(fmaf(s4.z, acc[2] + b4.z, h4.z), 0.f),
                fmaxf(fmaf(s4.w, acc[3] + b4.w, h4.w), 0.f));
    *(uint2*)&nf1b[(size_t)bn * 64 + ob] = d;
  }
}

// ---------- kernel B: fused MFMA message passing, register-slim ----------
// R14 base (slim body, setprio, idx/et prefetch) + GATHER-ONLY 1-deep prefetch
// (nb0_c/nb1_c, 8 regs; idx 2-deep, 2 regs). x load stays inline (streaming).
__global__ __launch_bounds__(256, 3) void k_fused(
    const float* __restrict__ node, const float* __restrict__ wfeat,
    const int* __restrict__ etype, const int* __restrict__ nn_idx,
    const u16* __restrict__ nf1b, const unsigned* __restrict__ blob,
    float* __restrict__ out_nf, float* __restrict__ out_wf) {

  __shared__ __align__(16) unsigned char sm[41600];  // 38912 frags + 2688 params
  __shared__ __align__(16) u16 nout_bf[16 * 64];     // 2048 B, swizzled
  __shared__ __align__(16) u16 Rx[4][512];           // 4096 B

  const int tid = threadIdx.x;
  for (int i = tid; i < 2432; i += 256)              // frag part: 9728 u32
    ((uint4*)sm)[i] = ((const uint4*)blob)[i];
  for (int i = tid; i < 168; i += 256)               // params: 672 u32
    ((uint4*)(sm + 38912))[i] = ((const uint4*)(blob + 11776))[i];

  const u16* th_p = (const u16*)sm;
  const u16* eW_p = (const u16*)(sm + 24576);
  const u16* gW_p = (const u16*)(sm + 30720);
  const u16* w1_p = (const u16*)(sm + 34816);
  const u16* w2_p = (const u16*)(sm + 36864);
  const float* par = (const float*)(sm + 38912);
  const float* tb_s  = par;
  const float* gb_s  = par + 192;
  const float* ns2_s = par + 256;
  const float* nb2_s = par + 320;
  const float* nsh2_s= par + 384;
  const float* eb_s  = par + 448;
  const float* ws1_s = par + 480;
  const float* wb1_s = par + 512;
  const float* wsh1_s= par + 544;
  const float* ws2_s = par + 576;
  const float* wb2_s = par + 608;
  const float* wsh2_s= par + 640;

  // bijective XCD chunking: nwg=2500, q=312, r=4
  const int pb = blockIdx.x;
  const int xcd = pb & 7, sub = pb >> 3;
  const int lb = (xcd < 4) ? (xcd * 313 + sub) : (1252 + (xcd - 4) * 312 + sub);
  const int nbase = lb * 16;

  const int l = tid & 63, wv = tid >> 6;  // wv 0..3
  const int el = l & 15, kg = l >> 4;
  u16* const Rn = &Rx[wv][0];
  const int eoff = nbase * 16 + wv * 16 + el;  // edge-array base for this lane

  __syncthreads();

  const f32x4 z4 = {0.f, 0.f, 0.f, 0.f};
  union UF { bf16x8 v; uint4 q; };

  // ---- gather-only prefetch state: nb one node ahead, idx two ahead ----
  int et_c, et_n, idx_n;
  bf16x8 nb0_c, nb1_c;
  {
    const int nid = nbase + wv;
    const int b0 = nid / N_;
    const int idx0 = nn_idx[eoff];
    et_c  = etype[eoff];
    idx_n = nn_idx[eoff + 64];
    et_n  = etype[eoff + 64];
    const u16* nbp = nf1b + ((size_t)b0 * N_ + idx0) * 64 + kg * 8;
    nb0_c = *(const bf16x8*)nbp;
    nb1_c = *(const bf16x8*)(nbp + 32);
  }

#pragma unroll 1
  for (int it = 0; it < 4; ++it) {
    const int nid = nbase + it * 4 + wv;
    const int b = nid / N_;
    const int n = nid - b * N_;
    const int nl = it * 4 + wv;  // 0..15

    const int et = et_c;
    const bf16x8 nbf0 = nb0_c, nbf1 = nb1_c;

    // ---- issue next node's gather early (idx already resident) ----
    if (it < 3) {
      const int nid2 = nbase + (it + 1) * 4 + wv;
      const int b2 = nid2 / N_;
      const u16* nbp = nf1b + ((size_t)b2 * N_ + idx_n) * 64 + kg * 8;
      nb0_c = *(const bf16x8*)nbp;
      nb1_c = *(const bf16x8*)(nbp + 32);
      et_c = et_n;
      if (it < 2) {
        idx_n = nn_idx[eoff + (it + 2) * 64];
        et_n  = etype[eoff + (it + 2) * 64];
      }
    }

    // x B-fragment direct from wfeat (inline; streaming, L2-friendly)
    UF xf;
    {
      const float* xp = wfeat + ((size_t)(b * 32 + kg * 8) * N_ + n) * 16 + el;
      float a[8];
#pragma unroll
      for (int j = 0; j < 8; ++j) a[j] = xp[(size_t)j * N_ * 16];
      xf.q.x = f2bf2(a[0], a[1]); xf.q.y = f2bf2(a[2], a[3]);
      xf.q.z = f2bf2(a[4], a[5]); xf.q.w = f2bf2(a[6], a[7]);
    }

    // ---- wf1 = relu(bn(wW1 @ x)) -> R ----
#pragma unroll
    for (int mt = 0; mt < 2; ++mt) {
      bf16x8 a = *(const bf16x8*)&w1_p[(mt * 64 + l) * 8];
      f32x4 wc = __builtin_amdgcn_mfma_f32_16x16x32_bf16(a, xf.v, z4, 0, 0, 0);
      int ob = mt * 16 + kg * 4;
      float4 s4 = *(const float4*)&ws1_s[ob];
      float4 b4 = *(const float4*)&wb1_s[ob];
      float4 h4 = *(const float4*)&wsh1_s[ob];
      uint2 d;
      d.x = f2bf2(fmaxf(fmaf(s4.x, wc[0] + b4.x, h4.x), 0.f),
                  fmaxf(fmaf(s4.y, wc[1] + b4.y, h4.y), 0.f));
      d.y = f2bf2(fmaxf(fmaf(s4.z, wc[2] + b4.z, h4.z), 0.f),
                  fmaxf(fmaf(s4.w, wc[3] + b4.w, h4.w), 0.f));
      *(uint2*)&Rn[((mt * 2 + (kg >> 1)) * 16 + el) * 8 + (kg & 1) * 4] = d;
    }
    const bf16x8 wff = *(const bf16x8*)&Rn[l * 8];

    // ---- fused gate + msg + reduce, per M-tile; only w4r[4] persists ----
    const unsigned mk0 = (et == 0) ? 0xffffffffu : 0u;
    const unsigned mk1 = (et == 1) ? 0xffffffffu : 0u;
    const unsigned mk2 = (et == 2) ? 0xffffffffu : 0u;
    const int b0s = el & 1, b1s = (el >> 1) & 1;
    float w4r[4];
#pragma unroll 2
    for (int mt = 0; mt < 4; ++mt) {
      // gate tile (K=32 over wf1)
      bf16x8 ga = *(const bf16x8*)&gW_p[(mt * 64 + l) * 8];
      __builtin_amdgcn_s_setprio(1);
      f32x4 gacc = __builtin_amdgcn_mfma_f32_16x16x32_bf16(ga, wff, z4, 0, 0, 0);
      // msg tile: 3 etypes x 2 K-steps into one f32x4
      f32x4 m4 = z4;
#pragma unroll
      for (int t = 0; t < 3; ++t) {
        unsigned msk = (t == 0) ? mk0 : ((t == 1) ? mk1 : mk2);
        UF b0u, b1u;
        b0u.v = nbf0; b1u.v = nbf1;
        b0u.q.x &= msk; b0u.q.y &= msk; b0u.q.z &= msk; b0u.q.w &= msk;
        b1u.q.x &= msk; b1u.q.y &= msk; b1u.q.z &= msk; b1u.q.w &= msk;
        bf16x8 a0 = *(const bf16x8*)&th_p[((t * 8 + mt * 2 + 0) * 64 + l) * 8];
        bf16x8 a1 = *(const bf16x8*)&th_p[((t * 8 + mt * 2 + 1) * 64 + l) * 8];
        m4 = __builtin_amdgcn_mfma_f32_16x16x32_bf16(a0, b0u.v, m4, 0, 0, 0);
        m4 = __builtin_amdgcn_mfma_f32_16x16x32_bf16(a1, b1u.v, m4, 0, 0, 0);
      }
      __builtin_amdgcn_s_setprio(0);
      // combine + sigmoid
      int ob = mt * 16 + kg * 4;
      float4 tb = *(const float4*)&tb_s[et * 64 + ob];
      float4 gb = *(const float4*)&gb_s[ob];
      float p0 = (m4[0] + tb.x) * sigm(gacc[0] + gb.x);
      float p1 = (m4[1] + tb.y) * sigm(gacc[1] + gb.y);
      float p2 = (m4[2] + tb.z) * sigm(gacc[2] + gb.z);
      float p3 = (m4[3] + tb.w) * sigm(gacc[3] + gb.w);
      // reduce stage 1 (xor 1) -> two survivors, stage 2 (xor 2) -> one
      float s, k0;
      s = b0s ? p0 : p1; k0 = b0s ? p1 : p0;
      float w8a = k0 + __shfl_xor(s, 1);
      s = b0s ? p2 : p3; k0 = b0s ? p3 : p2;
      float w8b = k0 + __shfl_xor(s, 1);
      s = b1s ? w8a : w8b; k0 = b1s ? w8b : w8a;
      w4r[mt] = k0 + __shfl_xor(s, 2);
    }
    // reduce stages 3-4
    {
      const int b2s = (el >> 2) & 1, b3s = (el >> 3) & 1;
      float s, k0;
      s = b2s ? w4r[0] : w4r[1]; k0 = b2s ? w4r[1] : w4r[0];
      float w2a = k0 + __shfl_xor(s, 4);
      s = b2s ? w4r[2] : w4r[3]; k0 = b2s ? w4r[3] : w4r[2];
      float w2b = k0 + __shfl_xor(s, 4);
      s = b3s ? w2a : w2b; k0 = b3s ? w2b : w2a;
      float z = k0 + __shfl_xor(s, 8);
      float no = fmaxf(z * 0.0625f, 0.f);
      int ch = ((el >> 2) << 4) + (kg << 2) + (el & 3);
      int su = (ch >> 3) ^ (nl & 7);
      nout_bf[nl * 64 + su * 8 + (ch & 7)] = f2bf(no);
    }

    // ---- edge conv + w_out epilogue (eacc transient per tile) -> R ----
    __builtin_amdgcn_s_setprio(1);
#pragma unroll
    for (int mt = 0; mt < 2; ++mt) {
      bf16x8 a0 = *(const bf16x8*)&eW_p[((mt * 3 + 0) * 64 + l) * 8];
      bf16x8 a1 = *(const bf16x8*)&eW_p[((mt * 3 + 1) * 64 + l) * 8];
      bf16x8 a2 = *(const bf16x8*)&eW_p[((mt * 3 + 2) * 64 + l) * 8];
      f32x4 acc = __builtin_amdgcn_mfma_f32_16x16x32_bf16(a0, wff, z4, 0, 0, 0);
      acc = __builtin_amdgcn_mfma_f32_16x16x32_bf16(a1, nbf0, acc, 0, 0, 0);
      acc = __builtin_amdgcn_mfma_f32_16x16x32_bf16(a2, nbf1, acc, 0, 0, 0);
      int ob = mt * 16 + kg * 4;
      float4 eb4 = *(const float4*)&eb_s[ob];
      uint2 d;
      d.x = f2bf2(fmaxf(acc[0] + eb4.x, 0.f), fmaxf(acc[1] + eb4.y, 0.f));
      d.y = f2bf2(fmaxf(acc[2] + eb4.z, 0.f), fmaxf(acc[3] + eb4.w, 0.f));
      *(uint2*)&Rn[((mt * 2 + (kg >> 1)) * 16 + el) * 8 + (kg & 1) * 4] = d;
    }
    __builtin_amdgcn_s_setprio(0);
    const bf16x8 wof = *(const bf16x8*)&Rn[l * 8];

    // ---- wf2 = relu(bn(wW2 @ w_out)) + wfeat residual, direct store ----
#pragma unroll
    for (int mt = 0; mt < 2; ++mt) {
      bf16x8 a = *(const bf16x8*)&w2_p[(mt * 64 + l) * 8];
      f32x4 fc = __builtin_amdgcn_mfma_f32_16x16x32_bf16(a, wof, z4, 0, 0, 0);
      int ob = mt * 16 + kg * 4;
      float4 s4 = *(const float4*)&ws2_s[ob];
      float4 b4 = *(const float4*)&wb2_s[ob];
      float4 h4 = *(const float4*)&wsh2_s[ob];
      float sv[4] = {s4.x, s4.y, s4.z, s4.w};
      float bv[4] = {b4.x, b4.y, b4.z, b4.w};
      float hv[4] = {h4.x, h4.y, h4.z, h4.w};
#pragma unroll
      for (int r = 0; r < 4; ++r) {
        int a2 = ((b * 32 + ob + r) * N_ + n) * 16 + el;
        float y = fmaxf(fmaf(sv[r], fc[r] + bv[r], hv[r]), 0.f);
        out_wf[a2] = y + wfeat[a2];
      }
    }
  }
  __syncthreads();

  // ---- phase 2: nf2 = relu(bn(nW2 @ n_out)) + node residual, via MFMA ----
  // 4 waves: wave wv = M-tile; 16 nodes; nW2 frags direct from global blob.
  {
    const int mt = wv;
    const int node_l = el;
    const int nid2 = nbase + node_l;
    const int b2 = nid2 / N_;
    const int n2 = nid2 - b2 * N_;
    const int sw = node_l & 7;
    const u16* nW2g = (const u16*)(blob + 9728);
    bf16x8 nb0 = *(const bf16x8*)&nout_bf[node_l * 64 + ((0 + kg) ^ sw) * 8];
    bf16x8 nb1 = *(const bf16x8*)&nout_bf[node_l * 64 + ((4 + kg) ^ sw) * 8];
    bf16x8 a0 = *(const bf16x8*)&nW2g[((mt * 2 + 0) * 64 + l) * 8];
    bf16x8 a1 = *(const bf16x8*)&nW2g[((mt * 2 + 1) * 64 + l) * 8];
    f32x4 acc = __builtin_amdgcn_mfma_f32_16x16x32_bf16(a0, nb0, z4, 0, 0, 0);
    acc = __builtin_amdgcn_mfma_f32_16x16x32_bf16(a1, nb1, acc, 0, 0, 0);
#pragma unroll
    for (int i = 0; i < 4; ++i) {
      int ch = mt * 16 + kg * 4 + i;
      int off = (b2 * 64 + ch) * N_ + n2;
      float y = fmaxf(fmaf(ns2_s[ch], acc[i] + nb2_s[ch], nsh2_s[ch]), 0.f);
      out_nf[off] = y + node[off];
    }
  }
}

extern "C" void kernel_launch(void* const* d_in, const int* in_sizes, int n_in,
                              void* d_out, int out_size, void* d_ws, size_t ws_size,
                              hipStream_t stream) {
  const float* node    = (const float*)d_in[0];
  const float* wfeat   = (const float*)d_in[1];
  const int*   etype   = (const int*)d_in[2];
  const int*   nn_idx  = (const int*)d_in[3];
  const float* nW1     = (const float*)d_in[4];
  const float* nb1     = (const float*)d_in[5];
  const float* ns1     = (const float*)d_in[6];
  const float* nsh1    = (const float*)d_in[7];
  const float* wW1     = (const float*)d_in[8];
  const float* wb1     = (const float*)d_in[9];
  const float* ws1     = (const float*)d_in[10];
  const float* wsh1    = (const float*)d_in[11];
  const float* theta   = (const float*)d_in[12];
  const float* theta_b = (const float*)d_in[13];
  const float* gateW   = (const float*)d_in[14];
  const float* gate_b  = (const float*)d_in[15];
  const float* edgeW   = (const float*)d_in[16];
  const float* edge_b  = (const float*)d_in[17];
  const float* nW2     = (const float*)d_in[18];
  const float* nb2     = (const float*)d_in[19];
  const float* ns2     = (const float*)d_in[20];
  const float* nsh2    = (const float*)d_in[21];
  const float* wW2     = (const float*)d_in[22];
  const float* wb2     = (const float*)d_in[23];
  const float* ws2     = (const float*)d_in[24];
  const float* wsh2    = (const float*)d_in[25];

  u16*      nf1b = (u16*)d_ws;                                   // 5.12 MB
  unsigned* blob = (unsigned*)((char*)d_ws + 5120000);           // 49.8 KB
  float* out_nf = (float*)d_out;
  float* out_wf = (float*)d_out + (size_t)B_ * 64 * N_;

  k_pack<<<1, 256, 0, stream>>>(theta, edgeW, gateW, wW1, wW2, nW2,
                                theta_b, gate_b, edge_b,
                                ws1, wb1, wsh1, ns2, nb2, nsh2, ws2, wb2, wsh2,
                                blob);
  k_nf1<<<625, 256, 0, stream>>>(node, nW1, nb1, ns1, nsh1, nf1b);
  k_fused<<<2500, 256, 0, stream>>>(node, wfeat, etype, nn_idx, nf1b, blob,
                                    out_nf, out_wf);
}

// Round 17
// 112.060 us; speedup vs baseline: 1.5393x; 1.3389x over previous
//
#include <hip/hip_runtime.h>
#include <hip/hip_bf16.h>
#include <stdint.h>

#define B_ 16
#define N_ 2500

typedef unsigned short u16;
typedef __attribute__((ext_vector_type(8))) short bf16x8;
typedef __attribute__((ext_vector_type(4))) float f32x4;

// cold-path manual RNE (k_pack only)
__device__ __forceinline__ u16 f2bf_sw(float f) {
  unsigned u = __float_as_uint(f);
  return (u16)((u + 0x7fffu + ((u >> 16) & 1u)) >> 16);
}
// hot-path HW convert
__device__ __forceinline__ u16 f2bf(float f) {
  __hip_bfloat16 h = __float2bfloat16(f);
  return __builtin_bit_cast(u16, h);
}
__device__ __forceinline__ unsigned f2bf2(float lo, float hi) {
  return (unsigned)f2bf(lo) | ((unsigned)f2bf(hi) << 16);
}
__device__ __forceinline__ float sigm(float x) {
  return __builtin_amdgcn_rcpf(1.f + __expf(-x));
}

// Blob layout (u32 units): th 0..6144, eW 6144..7680, gW 7680..8704,
// w1 8704..9216, w2 9216..9728, nW2 frags 9728..11776, params(f32) 11776..12448.
#define BLOB_U32 12448

// ---------- kernel P: pack all weights into fragment blob ----------
__global__ __launch_bounds__(256) void k_pack(
    const float* __restrict__ theta, const float* __restrict__ edgeW,
    const float* __restrict__ gateW, const float* __restrict__ wW1,
    const float* __restrict__ wW2, const float* __restrict__ nW2,
    const float* __restrict__ theta_b, const float* __restrict__ gate_b,
    const float* __restrict__ edge_b,
    const float* __restrict__ ws1, const float* __restrict__ wb1, const float* __restrict__ wsh1,
    const float* __restrict__ ns2, const float* __restrict__ nb2, const float* __restrict__ nsh2,
    const float* __restrict__ ws2, const float* __restrict__ wb2, const float* __restrict__ wsh2,
    unsigned* __restrict__ blob) {
  const int tid = threadIdx.x;
  for (int q = tid; q < 6144; q += 256) {  // theta frags: f = t*8 + mt*2 + h
    int f = q >> 8, lane = (q >> 2) & 63, jp = q & 3;
    int t = f >> 3, mt = (f >> 1) & 3, h = f & 1;
    int el = lane & 15, kg = lane >> 4;
    const float* s = theta + ((size_t)t * 64 + mt * 16 + el) * 64 + h * 32 + kg * 8 + jp * 2;
    blob[q] = (unsigned)f2bf_sw(s[0]) | ((unsigned)f2bf_sw(s[1]) << 16);
  }
  for (int q = tid; q < 1536; q += 256) {  // edgeW frags: f = mt*3 + s
    int f = q >> 8, lane = (q >> 2) & 63, jp = q & 3;
    int mt = f / 3, ss = f - mt * 3;
    int el = lane & 15, kg = lane >> 4;
    const float* s = edgeW + ((size_t)mt * 16 + el) * 96 + ss * 32 + kg * 8 + jp * 2;
    blob[6144 + q] = (unsigned)f2bf_sw(s[0]) | ((unsigned)f2bf_sw(s[1]) << 16);
  }
  for (int q = tid; q < 1024; q += 256) {  // gateW frags: f = mt
    int f = q >> 8, lane = (q >> 2) & 63, jp = q & 3;
    int el = lane & 15, kg = lane >> 4;
    const float* s = gateW + ((size_t)f * 16 + el) * 32 + kg * 8 + jp * 2;
    blob[7680 + q] = (unsigned)f2bf_sw(s[0]) | ((unsigned)f2bf_sw(s[1]) << 16);
  }
  for (int q = tid; q < 512; q += 256) {  // wW1/wW2 frags: f = mt
    int f = q >> 8, lane = (q >> 2) & 63, jp = q & 3;
    int el = lane & 15, kg = lane >> 4;
    const float* s1 = wW1 + (size_t)(f * 16 + el) * 32 + kg * 8 + jp * 2;
    const float* s2 = wW2 + (size_t)(f * 16 + el) * 32 + kg * 8 + jp * 2;
    blob[8704 + q] = (unsigned)f2bf_sw(s1[0]) | ((unsigned)f2bf_sw(s1[1]) << 16);
    blob[9216 + q] = (unsigned)f2bf_sw(s2[0]) | ((unsigned)f2bf_sw(s2[1]) << 16);
  }
  for (int q = tid; q < 2048; q += 256) {  // nW2 frags: f = mt*2 + h
    int f = q >> 8, lane = (q >> 2) & 63, jp = q & 3;
    int mt = f >> 1, h = f & 1;
    int el = lane & 15, kg = lane >> 4;
    const float* s = nW2 + (size_t)(mt * 16 + el) * 64 + h * 32 + kg * 8 + jp * 2;
    blob[9728 + q] = (unsigned)f2bf_sw(s[0]) | ((unsigned)f2bf_sw(s[1]) << 16);
  }
  float* bf = (float*)blob;
  for (int i = tid; i < 672; i += 256) {
    float v;
    if (i < 192)      v = theta_b[i];
    else if (i < 256) v = gate_b[i - 192];
    else if (i < 320) v = ns2[i - 256];
    else if (i < 384) v = nb2[i - 320];
    else if (i < 448) v = nsh2[i - 384];
    else if (i < 480) v = edge_b[i - 448];
    else if (i < 512) v = ws1[i - 480];
    else if (i < 544) v = wb1[i - 512];
    else if (i < 576) v = wsh1[i - 544];
    else if (i < 608) v = ws2[i - 576];
    else if (i < 640) v = wb2[i - 608];
    else              v = wsh2[i - 640];
    bf[11776 + i] = v;
  }
}

// ---------- kernel A: nf1 = relu(bn(nW1 @ node)) -> bf16 [b*N+n][64], MFMA ----------
__global__ __launch_bounds__(256) void k_nf1(
    const float* __restrict__ node, const float* __restrict__ W,
    const float* __restrict__ bia, const float* __restrict__ sc,
    const float* __restrict__ sh, u16* __restrict__ nf1b) {
  __shared__ __align__(16) u16 W_p[8 * 64 * 8];
  __shared__ float bia_s[64], sc_s[64], sh_s[64];
  const int tid = threadIdx.x;
  for (int q = tid; q < 2048; q += 256) {
    int f = q >> 8, lane = (q >> 2) & 63, jp = q & 3;
    int mt = f >> 1, h = f & 1;
    int fel = lane & 15, fkg = lane >> 4;
    const float* src = W + (size_t)(mt * 16 + fel) * 64 + h * 32 + fkg * 8 + jp * 2;
    ((unsigned*)W_p)[q] = f2bf2(src[0], src[1]);
  }
  if (tid < 64) { bia_s[tid] = bia[tid]; sc_s[tid] = sc[tid]; sh_s[tid] = sh[tid]; }
  __syncthreads();

  const int l = tid & 63, wv = tid >> 6;
  const int el = l & 15, kg = l >> 4;
  const int bn = blockIdx.x * 64 + wv * 16 + el;
  const int b = bn / N_;
  const int n = bn - b * N_;

  union UF { bf16x8 v; uint4 q; } xb0, xb1;
  const float* xp0 = node + (size_t)(b * 64 + kg * 8) * N_ + n;
  const float* xp1 = node + (size_t)(b * 64 + 32 + kg * 8) * N_ + n;
  {
    float a0[8], a1[8];
#pragma unroll
    for (int j = 0; j < 8; ++j) { a0[j] = xp0[(size_t)j * N_]; a1[j] = xp1[(size_t)j * N_]; }
    xb0.q.x = f2bf2(a0[0], a0[1]); xb0.q.y = f2bf2(a0[2], a0[3]);
    xb0.q.z = f2bf2(a0[4], a0[5]); xb0.q.w = f2bf2(a0[6], a0[7]);
    xb1.q.x = f2bf2(a1[0], a1[1]); xb1.q.y = f2bf2(a1[2], a1[3]);
    xb1.q.z = f2bf2(a1[4], a1[5]); xb1.q.w = f2bf2(a1[6], a1[7]);
  }
  const f32x4 z4 = {0.f, 0.f, 0.f, 0.f};
#pragma unroll
  for (int mt = 0; mt < 4; ++mt) {
    bf16x8 a0 = *(const bf16x8*)&W_p[((mt * 2 + 0) * 64 + l) * 8];
    bf16x8 a1 = *(const bf16x8*)&W_p[((mt * 2 + 1) * 64 + l) * 8];
    f32x4 acc = __builtin_amdgcn_mfma_f32_16x16x32_bf16(a0, xb0.v, z4, 0, 0, 0);
    acc = __builtin_amdgcn_mfma_f32_16x16x32_bf16(a1, xb1.v, acc, 0, 0, 0);
    int ob = mt * 16 + kg * 4;
    float4 s4 = *(const float4*)&sc_s[ob];
    float4 b4 = *(const float4*)&bia_s[ob];
    float4 h4 = *(const float4*)&sh_s[ob];
    uint2 d;
    d.x = f2bf2(fmaxf(fmaf(s4.x, acc[0] + b4.x, h4.x), 0.f),
                fmaxf(fmaf(s4.y, acc[1] + b4.y, h4.y), 0.f));
    d.y = f2bf2(fmaxf(fmaf(s4.z, acc[2] + b4.z, h4.z), 0.f),
                fmaxf(fmaf(s4.w, acc[3] + b4.w, h4.w), 0.f));
    *(uint2*)&nf1b[(size_t)bn * 64 + ob] = d;
  }
}

// ---------- kernel B: fused MFMA message passing, register-slim ----------
// Champion configuration (R14): slim body, setprio around MFMA clusters,
// idx/etype 1-deep prefetch only. (256,3): no spill at 3 waves/SIMD.
__global__ __launch_bounds__(256, 3) void k_fused(
    const float* __restrict__ node, const float* __restrict__ wfeat,
    const int* __restrict__ etype, const int* __restrict__ nn_idx,
    const u16* __restrict__ nf1b, const unsigned* __restrict__ blob,
    float* __restrict__ out_nf, float* __restrict__ out_wf) {

  __shared__ __align__(16) unsigned char sm[41600];  // 38912 frags + 2688 params
  __shared__ __align__(16) u16 nout_bf[16 * 64];     // 2048 B, swizzled
  __shared__ __align__(16) u16 Rx[4][512];           // 4096 B

  const int tid = threadIdx.x;
  for (int i = tid; i < 2432; i += 256)              // frag part: 9728 u32
    ((uint4*)sm)[i] = ((const uint4*)blob)[i];
  for (int i = tid; i < 168; i += 256)               // params: 672 u32
    ((uint4*)(sm + 38912))[i] = ((const uint4*)(blob + 11776))[i];

  const u16* th_p = (const u16*)sm;
  const u16* eW_p = (const u16*)(sm + 24576);
  const u16* gW_p = (const u16*)(sm + 30720);
  const u16* w1_p = (const u16*)(sm + 34816);
  const u16* w2_p = (const u16*)(sm + 36864);
  const float* par = (const float*)(sm + 38912);
  const float* tb_s  = par;
  const float* gb_s  = par + 192;
  const float* ns2_s = par + 256;
  const float* nb2_s = par + 320;
  const float* nsh2_s= par + 384;
  const float* eb_s  = par + 448;
  const float* ws1_s = par + 480;
  const float* wb1_s = par + 512;
  const float* wsh1_s= par + 544;
  const float* ws2_s = par + 576;
  const float* wb2_s = par + 608;
  const float* wsh2_s= par + 640;

  // bijective XCD chunking: nwg=2500, q=312, r=4
  const int pb = blockIdx.x;
  const int xcd = pb & 7, sub = pb >> 3;
  const int lb = (xcd < 4) ? (xcd * 313 + sub) : (1252 + (xcd - 4) * 312 + sub);
  const int nbase = lb * 16;

  const int l = tid & 63, wv = tid >> 6;  // wv 0..3
  const int el = l & 15, kg = l >> 4;
  u16* const Rn = &Rx[wv][0];
  const int eoff = nbase * 16 + wv * 16 + el;  // edge-array base for this lane

  __syncthreads();

  const f32x4 z4 = {0.f, 0.f, 0.f, 0.f};
  union UF { bf16x8 v; uint4 q; };

  // 1-deep idx/etype prefetch (heads the per-node dependence chain)
  int idx_c = nn_idx[eoff];
  int et_c  = etype[eoff];

#pragma unroll 1
  for (int it = 0; it < 4; ++it) {
    const int nid = nbase + it * 4 + wv;
    const int b = nid / N_;
    const int n = nid - b * N_;
    const int nl = it * 4 + wv;  // 0..15

    const int idx = idx_c;
    const int et  = et_c;
    if (it < 3) {
      idx_c = nn_idx[eoff + (it + 1) * 64];
      et_c  = etype[eoff + (it + 1) * 64];
    }

    // nb B-fragments from gather
    const u16* nbp = nf1b + ((size_t)b * N_ + idx) * 64 + kg * 8;
    const bf16x8 nbf0 = *(const bf16x8*)nbp;
    const bf16x8 nbf1 = *(const bf16x8*)(nbp + 32);

    // x B-fragment direct from wfeat
    UF xf;
    {
      const float* xp = wfeat + ((size_t)(b * 32 + kg * 8) * N_ + n) * 16 + el;
      float a[8];
#pragma unroll
      for (int j = 0; j < 8; ++j) a[j] = xp[(size_t)j * N_ * 16];
      xf.q.x = f2bf2(a[0], a[1]); xf.q.y = f2bf2(a[2], a[3]);
      xf.q.z = f2bf2(a[4], a[5]); xf.q.w = f2bf2(a[6], a[7]);
    }

    // ---- wf1 = relu(bn(wW1 @ x)) -> R ----
#pragma unroll
    for (int mt = 0; mt < 2; ++mt) {
      bf16x8 a = *(const bf16x8*)&w1_p[(mt * 64 + l) * 8];
      f32x4 wc = __builtin_amdgcn_mfma_f32_16x16x32_bf16(a, xf.v, z4, 0, 0, 0);
      int ob = mt * 16 + kg * 4;
      float4 s4 = *(const float4*)&ws1_s[ob];
      float4 b4 = *(const float4*)&wb1_s[ob];
      float4 h4 = *(const float4*)&wsh1_s[ob];
      uint2 d;
      d.x = f2bf2(fmaxf(fmaf(s4.x, wc[0] + b4.x, h4.x), 0.f),
                  fmaxf(fmaf(s4.y, wc[1] + b4.y, h4.y), 0.f));
      d.y = f2bf2(fmaxf(fmaf(s4.z, wc[2] + b4.z, h4.z), 0.f),
                  fmaxf(fmaf(s4.w, wc[3] + b4.w, h4.w), 0.f));
      *(uint2*)&Rn[((mt * 2 + (kg >> 1)) * 16 + el) * 8 + (kg & 1) * 4] = d;
    }
    const bf16x8 wff = *(const bf16x8*)&Rn[l * 8];

    // ---- fused gate + msg + reduce, per M-tile; only w4r[4] persists ----
    const unsigned mk0 = (et == 0) ? 0xffffffffu : 0u;
    const unsigned mk1 = (et == 1) ? 0xffffffffu : 0u;
    const unsigned mk2 = (et == 2) ? 0xffffffffu : 0u;
    const int b0s = el & 1, b1s = (el >> 1) & 1;
    float w4r[4];
#pragma unroll 2
    for (int mt = 0; mt < 4; ++mt) {
      // gate tile (K=32 over wf1)
      bf16x8 ga = *(const bf16x8*)&gW_p[(mt * 64 + l) * 8];
      __builtin_amdgcn_s_setprio(1);
      f32x4 gacc = __builtin_amdgcn_mfma_f32_16x16x32_bf16(ga, wff, z4, 0, 0, 0);
      // msg tile: 3 etypes x 2 K-steps into one f32x4
      f32x4 m4 = z4;
#pragma unroll
      for (int t = 0; t < 3; ++t) {
        unsigned msk = (t == 0) ? mk0 : ((t == 1) ? mk1 : mk2);
        UF b0u, b1u;
        b0u.v = nbf0; b1u.v = nbf1;
        b0u.q.x &= msk; b0u.q.y &= msk; b0u.q.z &= msk; b0u.q.w &= msk;
        b1u.q.x &= msk; b1u.q.y &= msk; b1u.q.z &= msk; b1u.q.w &= msk;
        bf16x8 a0 = *(const bf16x8*)&th_p[((t * 8 + mt * 2 + 0) * 64 + l) * 8];
        bf16x8 a1 = *(const bf16x8*)&th_p[((t * 8 + mt * 2 + 1) * 64 + l) * 8];
        m4 = __builtin_amdgcn_mfma_f32_16x16x32_bf16(a0, b0u.v, m4, 0, 0, 0);
        m4 = __builtin_amdgcn_mfma_f32_16x16x32_bf16(a1, b1u.v, m4, 0, 0, 0);
      }
      __builtin_amdgcn_s_setprio(0);
      // combine + sigmoid
      int ob = mt * 16 + kg * 4;
      float4 tb = *(const float4*)&tb_s[et * 64 + ob];
      float4 gb = *(const float4*)&gb_s[ob];
      float p0 = (m4[0] + tb.x) * sigm(gacc[0] + gb.x);
      float p1 = (m4[1] + tb.y) * sigm(gacc[1] + gb.y);
      float p2 = (m4[2] + tb.z) * sigm(gacc[2] + gb.z);
      float p3 = (m4[3] + tb.w) * sigm(gacc[3] + gb.w);
      // reduce stage 1 (xor 1) -> two survivors, stage 2 (xor 2) -> one
      float s, k0;
      s = b0s ? p0 : p1; k0 = b0s ? p1 : p0;
      float w8a = k0 + __shfl_xor(s, 1);
      s = b0s ? p2 : p3; k0 = b0s ? p3 : p2;
      float w8b = k0 + __shfl_xor(s, 1);
      s = b1s ? w8a : w8b; k0 = b1s ? w8b : w8a;
      w4r[mt] = k0 + __shfl_xor(s, 2);
    }
    // reduce stages 3-4
    {
      const int b2s = (el >> 2) & 1, b3s = (el >> 3) & 1;
      float s, k0;
      s = b2s ? w4r[0] : w4r[1]; k0 = b2s ? w4r[1] : w4r[0];
      float w2a = k0 + __shfl_xor(s, 4);
      s = b2s ? w4r[2] : w4r[3]; k0 = b2s ? w4r[3] : w4r[2];
      float w2b = k0 + __shfl_xor(s, 4);
      s = b3s ? w2a : w2b; k0 = b3s ? w2b : w2a;
      float z = k0 + __shfl_xor(s, 8);
      float no = fmaxf(z * 0.0625f, 0.f);
      int ch = ((el >> 2) << 4) + (kg << 2) + (el & 3);
      int su = (ch >> 3) ^ (nl & 7);
      nout_bf[nl * 64 + su * 8 + (ch & 7)] = f2bf(no);
    }

    // ---- edge conv + w_out epilogue (eacc transient per tile) -> R ----
    __builtin_amdgcn_s_setprio(1);
#pragma unroll
    for (int mt = 0; mt < 2; ++mt) {
      bf16x8 a0 = *(const bf16x8*)&eW_p[((mt * 3 + 0) * 64 + l) * 8];
      bf16x8 a1 = *(const bf16x8*)&eW_p[((mt * 3 + 1) * 64 + l) * 8];
      bf16x8 a2 = *(const bf16x8*)&eW_p[((mt * 3 + 2) * 64 + l) * 8];
      f32x4 acc = __builtin_amdgcn_mfma_f32_16x16x32_bf16(a0, wff, z4, 0, 0, 0);
      acc = __builtin_amdgcn_mfma_f32_16x16x32_bf16(a1, nbf0, acc, 0, 0, 0);
      acc = __builtin_amdgcn_mfma_f32_16x16x32_bf16(a2, nbf1, acc, 0, 0, 0);
      int ob = mt * 16 + kg * 4;
      float4 eb4 = *(const float4*)&eb_s[ob];
      uint2 d;
      d.x = f2bf2(fmaxf(acc[0] + eb4.x, 0.f), fmaxf(acc[1] + eb4.y, 0.f));
      d.y = f2bf2(fmaxf(acc[2] + eb4.z, 0.f), fmaxf(acc[3] + eb4.w, 0.f));
      *(uint2*)&Rn[((mt * 2 + (kg >> 1)) * 16 + el) * 8 + (kg & 1) * 4] = d;
    }
    __builtin_amdgcn_s_setprio(0);
    const bf16x8 wof = *(const bf16x8*)&Rn[l * 8];

    // ---- wf2 = relu(bn(wW2 @ w_out)) + wfeat residual, direct store ----
#pragma unroll
    for (int mt = 0; mt < 2; ++mt) {
      bf16x8 a = *(const bf16x8*)&w2_p[(mt * 64 + l) * 8];
      f32x4 fc = __builtin_amdgcn_mfma_f32_16x16x32_bf16(a, wof, z4, 0, 0, 0);
      int ob = mt * 16 + kg * 4;
      float4 s4 = *(const float4*)&ws2_s[ob];
      float4 b4 = *(const float4*)&wb2_s[ob];
      float4 h4 = *(const float4*)&wsh2_s[ob];
      float sv[4] = {s4.x, s4.y, s4.z, s4.w};
      float bv[4] = {b4.x, b4.y, b4.z, b4.w};
      float hv[4] = {h4.x, h4.y, h4.z, h4.w};
#pragma unroll
      for (int r = 0; r < 4; ++r) {
        int a2 = ((b * 32 + ob + r) * N_ + n) * 16 + el;
        float y = fmaxf(fmaf(sv[r], fc[r] + bv[r], hv[r]), 0.f);
        out_wf[a2] = y + wfeat[a2];
      }
    }
  }
  __syncthreads();

  // ---- phase 2: nf2 = relu(bn(nW2 @ n_out)) + node residual, via MFMA ----
  // 4 waves: wave wv = M-tile; 16 nodes; nW2 frags direct from global blob.
  {
    const int mt = wv;
    const int node_l = el;
    const int nid2 = nbase + node_l;
    const int b2 = nid2 / N_;
    const int n2 = nid2 - b2 * N_;
    const int sw = node_l & 7;
    const u16* nW2g = (const u16*)(blob + 9728);
    bf16x8 nb0 = *(const bf16x8*)&nout_bf[node_l * 64 + ((0 + kg) ^ sw) * 8];
    bf16x8 nb1 = *(const bf16x8*)&nout_bf[node_l * 64 + ((4 + kg) ^ sw) * 8];
    bf16x8 a0 = *(const bf16x8*)&nW2g[((mt * 2 + 0) * 64 + l) * 8];
    bf16x8 a1 = *(const bf16x8*)&nW2g[((mt * 2 + 1) * 64 + l) * 8];
    f32x4 acc = __builtin_amdgcn_mfma_f32_16x16x32_bf16(a0, nb0, z4, 0, 0, 0);
    acc = __builtin_amdgcn_mfma_f32_16x16x32_bf16(a1, nb1, acc, 0, 0, 0);
#pragma unroll
    for (int i = 0; i < 4; ++i) {
      int ch = mt * 16 + kg * 4 + i;
      int off = (b2 * 64 + ch) * N_ + n2;
      float y = fmaxf(fmaf(ns2_s[ch], acc[i] + nb2_s[ch], nsh2_s[ch]), 0.f);
      out_nf[off] = y + node[off];
    }
  }
}

extern "C" void kernel_launch(void* const* d_in, const int* in_sizes, int n_in,
                              void* d_out, int out_size, void* d_ws, size_t ws_size,
                              hipStream_t stream) {
  const float* node    = (const float*)d_in[0];
  const float* wfeat   = (const float*)d_in[1];
  const int*   etype   = (const int*)d_in[2];
  const int*   nn_idx  = (const int*)d_in[3];
  const float* nW1     = (const float*)d_in[4];
  const float* nb1     = (const float*)d_in[5];
  const float* ns1     = (const float*)d_in[6];
  const float* nsh1    = (const float*)d_in[7];
  const float* wW1     = (const float*)d_in[8];
  const float* wb1     = (const float*)d_in[9];
  const float* ws1     = (const float*)d_in[10];
  const float* wsh1    = (const float*)d_in[11];
  const float* theta   = (const float*)d_in[12];
  const float* theta_b = (const float*)d_in[13];
  const float* gateW   = (const float*)d_in[14];
  const float* gate_b  = (const float*)d_in[15];
  const float* edgeW   = (const float*)d_in[16];
  const float* edge_b  = (const float*)d_in[17];
  const float* nW2     = (const float*)d_in[18];
  const float* nb2     = (const float*)d_in[19];
  const float* ns2     = (const float*)d_in[20];
  const float* nsh2    = (const float*)d_in[21];
  const float* wW2     = (const float*)d_in[22];
  const float* wb2     = (const float*)d_in[23];
  const float* ws2     = (const float*)d_in[24];
  const float* wsh2    = (const float*)d_in[25];

  u16*      nf1b = (u16*)d_ws;                                   // 5.12 MB
  unsigned* blob = (unsigned*)((char*)d_ws + 5120000);           // 49.8 KB
  float* out_nf = (float*)d_out;
  float* out_wf = (float*)d_out + (size_t)B_ * 64 * N_;

  k_pack<<<1, 256, 0, stream>>>(theta, edgeW, gateW, wW1, wW2, nW2,
                                theta_b, gate_b, edge_b,
                                ws1, wb1, wsh1, ns2, nb2, nsh2, ws2, wb2, wsh2,
                                blob);
  k_nf1<<<625, 256, 0, stream>>>(node, nW1, nb1, ns1, nsh1, nf1b);
  k_fused<<<2500, 256, 0, stream>>>(node, wfeat, etype, nn_idx, nf1b, blob,
                                    out_nf, out_wf);
}